// Round 14
// baseline (159.932 us; speedup 1.0000x reference)
//
#include <hip/hip_runtime.h>

#define B_SZ 4096
#define F_SZ 24
#define V_SZ 1000
#define D_SZ 32
#define RED  8
#define FD   768      // F*D
#define COMB 1536
#define H0   1024
#define H1   512
#define EPS  1e-5f

typedef __bf16 bf16x8 __attribute__((ext_vector_type(8)));
typedef float  f32x16 __attribute__((ext_vector_type(16)));
typedef const __attribute__((address_space(1))) unsigned int* gptr_t;
typedef       __attribute__((address_space(3))) unsigned int* lptr_t;

__device__ __forceinline__ float bf2f(unsigned short u) {
    union { unsigned int i; float f; } v; v.i = ((unsigned int)u) << 16; return v.f;
}
__device__ __forceinline__ unsigned short f2bf(float f) {
    union { float f; unsigned int i; } v; v.f = f;
    unsigned int u = v.i;
    return (unsigned short)((u + 0x7FFFu + ((u >> 16) & 1u)) >> 16);
}
__device__ __forceinline__ unsigned int pack2(float a, float b) {
    return (unsigned int)f2bf(a) | ((unsigned int)f2bf(b) << 16);
}

// ---------- mega-prep: gather/SENet + Wt reorder (vec4) + w0/w1 transpose + zero sums ----------
__global__ __launch_bounds__(256) void prep_gather(
        const int* __restrict__ x, const float* __restrict__ emb,
        const float* __restrict__ lint, const float* __restrict__ sw1,
        const float* __restrict__ sw2, const float* __restrict__ bw,
        const float* __restrict__ w0, const float* __restrict__ w1,
        unsigned short* __restrict__ Xbf, unsigned short* __restrict__ Wt,
        unsigned short* __restrict__ w0t, unsigned short* __restrict__ w1t,
        float* __restrict__ lin, float* __restrict__ sums) {
    int bid = blockIdx.x;
    int tid = threadIdx.x;
    if (bid < 1024) {
        int w = tid >> 6, lane = tid & 63;
        int b = bid * 4 + w;
        __shared__ int   xi[4][F_SZ];
        __shared__ float e[4][F_SZ][D_SZ];
        __shared__ float Z[4][F_SZ];
        __shared__ float r1[4][RED];
        __shared__ float Afac[4][F_SZ];
        if (lane < F_SZ) xi[w][lane] = x[b * F_SZ + lane];
        __syncthreads();
        #pragma unroll
        for (int it = 0; it < 3; it++) {
            int idx = it * 64 + lane;
            int f = idx >> 3, k4 = (idx & 7) * 4;
            float4 v = *(const float4*)&emb[((size_t)f * V_SZ + xi[w][f]) * D_SZ + k4];
            *(float4*)&e[w][f][k4] = v;
        }
        __syncthreads();
        if (lane < F_SZ) {
            float s = 0.f;
            #pragma unroll
            for (int k = 0; k < D_SZ; k++) s += e[w][lane][k];
            Z[w][lane] = s * (1.f / D_SZ);
        }
        __syncthreads();
        if (lane < RED) {
            float s = 0.f;
            #pragma unroll
            for (int f = 0; f < F_SZ; f++) s += Z[w][f] * sw1[lane * F_SZ + f];
            r1[w][lane] = fmaxf(s, 0.f);
        }
        __syncthreads();
        if (lane < F_SZ) {
            float s = 0.f;
            #pragma unroll
            for (int r = 0; r < RED; r++) s += r1[w][r] * sw2[lane * RED + r];
            Afac[w][lane] = 1.f / (1.f + expf(-s));
        }
        __syncthreads();
        #pragma unroll
        for (int it = 0; it < 3; it++) {
            int idx = it * 64 + lane;
            int f = idx >> 3, k4 = (idx & 7) * 4;
            const float* p = &e[w][f][k4];
            uint2 u, us;
            u.x = pack2(p[0], p[1]); u.y = pack2(p[2], p[3]);
            float a = Afac[w][f];
            us.x = pack2(p[0] * a, p[1] * a); us.y = pack2(p[2] * a, p[3] * a);
            *(uint2*)&Xbf[(size_t)b * FD + idx * 4] = u;
            *(uint2*)&Xbf[(size_t)(B_SZ + b) * FD + idx * 4] = us;
        }
        float lv = (lane < F_SZ) ? lint[lane * V_SZ + xi[w][lane]] : 0.f;
        #pragma unroll
        for (int off = 32; off > 0; off >>= 1) lv += __shfl_down(lv, off);
        if (lane == 0) lin[b] = lv;
    } else if (bid < 1600) {
        // Wt reorder, 4 elems/thread: all 4 share (i,j,k) run since 768%4==0
        int o4 = ((bid - 1024) * 256 + tid) * 4;
        int ik = o4 / FD, jl = o4 - ik * FD;
        int i = ik >> 5, k = ik & 31, j = jl >> 5, l = jl & 31;
        uint2 ov;
        if (i == j) {
            ov.x = 0u; ov.y = 0u;
        } else {
            float4 v = *(const float4*)&bw[(((size_t)i * F_SZ + j) * D_SZ + k) * D_SZ + l];
            ov.x = pack2(v.x, v.y); ov.y = pack2(v.z, v.w);
        }
        *(uint2*)&Wt[o4] = ov;
    } else if (bid < 3648) {
        __shared__ float tile[32][33];
        const float* in; unsigned short* out; int K, N, bx, by;
        if (bid < 3136) { int t = bid - 1600; in = w0; out = w0t; K = COMB; N = H0; bx = t & 31; by = t >> 5; }
        else            { int t = bid - 3136; in = w1; out = w1t; K = H0;   N = H1; bx = t & 15; by = t >> 4; }
        int tx = tid & 31, ty = tid >> 5;
        int n0 = bx * 32, k0 = by * 32;
        #pragma unroll
        for (int r = 0; r < 32; r += 8)
            tile[ty + r][tx] = in[(size_t)(k0 + ty + r) * N + n0 + tx];
        __syncthreads();
        #pragma unroll
        for (int r = 0; r < 32; r += 8)
            out[(size_t)(n0 + ty + r) * K + k0 + tx] = f2bf(tile[tx][ty + r]);
    } else {
        int o = (bid - 3648) * 256 + tid;   // 3072 floats
        sums[o] = 0.f;
    }
}

// ---------- MFMA GEMM: C = A[M,K](bf16) @ Bt[N,K]^T(bf16), TMxTN tile, BK=32*NSUB ----------
// 32x32x16 MFMA microtiles; LDS 16B-chunk XOR swizzle keeps global_load_lds lane-contiguity.
// MODE 0: C = Xbf .* S -> Obf[4096,1536] (epilogue Xbf prefetched before Cst barrier).
// MODE 1: +bias, bf16 store, fused BN stats. MODE 2: A = relu(bn(Araw)) via prefetched VGPRs.
// All latency chains front-loaded: bias pre-K-loop, MODE2 first-A before sc_s barrier.
template<int MODE, int K, int N, int TM, int TN, int GX, int GY, int NSUB>
__global__ __launch_bounds__(256) void mfma_gemm(
        const unsigned short* __restrict__ A,
        const unsigned short* __restrict__ Bt,
        const float* __restrict__ bias,
        const unsigned short* __restrict__ Xbf,
        unsigned short* __restrict__ Obf,
        float* __restrict__ sum, float* __restrict__ sumsq,
        const float* __restrict__ psum, const float* __restrict__ psumsq,
        const float* __restrict__ g, const float* __restrict__ be) {
    constexpr int MI2 = TM / 64, NI2 = TN / 64;       // 32x32 tiles per wave
    constexpr int CLD = TN + 4;                       // padded fp32 C stride
    constexpr int STAGE = (TM + TN) * NSUB * 64;      // bytes: 32*NSUB kcols x 2B
    constexpr int CST   = TM * CLD * 4;
    constexpr int SMEM  = STAGE > CST ? STAGE : CST;
    __shared__ __align__(16) char smem[SMEM];
    unsigned short* Abuf = (unsigned short*)smem;                      // [NSUB][TM*32]
    unsigned short* Bbuf = (unsigned short*)(smem + TM * NSUB * 64);   // [NSUB][TN*32]
    float* Cst = (float*)smem;
    __shared__ float sc_s[MODE == 2 ? K : 1];
    __shared__ float sh_s[MODE == 2 ? K : 1];
    const int tid  = threadIdx.x;
    const int lane = tid & 63, wv = tid >> 6;
    const int wm = (wv >> 1) * (TM / 2), wn = (wv & 1) * (TN / 2);
    const int m32 = lane & 31, hi = lane >> 5;        // 32x32 frag coords
    const int rsw = (m32 >> 1) & 3;                   // read-side swizzle key
    const int bid = blockIdx.x;
    const int xcd = bid & 7, slot = bid >> 3;
    const int rowb = xcd * (GY / 8) + slot / GX;
    const int colb = slot % GX;
    const int bm = rowb * TM, bn = colb * TN;
    const int srow = tid >> 2;                        // 0..63
    const int skc  = (((tid & 3) ^ ((tid >> 3) & 3)) * 8);  // swizzled k-offset (shorts)

    // front-loaded independent loads: first A panel (MODE 2) + bias scalar
    uint4 hvA[NSUB];
    if (MODE == 2) {
        #pragma unroll
        for (int s = 0; s < NSUB; s++)
            hvA[s] = *(const uint4*)&A[(size_t)(bm + srow) * K + 32 * s + skc];
    }
    float bvr = 0.f;
    if (MODE != 0) bvr = bias[bn + wn + m32];

    if (MODE == 2) {
        #pragma unroll
        for (int q = 0; q < K / 256; q++) {
            int c = q * 256 + tid;
            float m = psum[c] * (1.f / B_SZ);
            float var = psumsq[c] * (1.f / B_SZ) - m * m;
            float rstd = rsqrtf(var + EPS);
            float sc = g[c] * rstd;
            sc_s[c] = sc;
            sh_s[c] = be[c] - m * sc;
        }
        __syncthreads();
    }

    f32x16 acc[MI2][NI2];
    #pragma unroll
    for (int i = 0; i < MI2; i++)
        #pragma unroll
        for (int j = 0; j < NI2; j++)
            #pragma unroll
            for (int r = 0; r < 16; r++) acc[i][j][r] = 0.f;

    for (int k0 = 0; k0 < K; k0 += 32 * NSUB) {
        // B DMA first: overlaps MODE 2's A VALU processing below
        #pragma unroll
        for (int s = 0; s < NSUB; s++)
            #pragma unroll
            for (int c = 0; c < TN / 64; c++) {
                const unsigned short* gb = Bt + (size_t)(bn + c * 64 + srow) * K + k0 + 32 * s + skc;
                char* lb = smem + TM * NSUB * 64 + s * TN * 64 + c * 4096 + wv * 1024;
                __builtin_amdgcn_global_load_lds((gptr_t)gb, (lptr_t)lb, 16, 0, 0);
            }
        if (MODE == 2) {
            #pragma unroll
            for (int s = 0; s < NSUB; s++) {
                unsigned int uu[4] = {hvA[s].x, hvA[s].y, hvA[s].z, hvA[s].w};
                unsigned int oo[4];
                #pragma unroll
                for (int q = 0; q < 4; q++) {
                    int c = k0 + 32 * s + skc + 2 * q;
                    float v0 = bf2f((unsigned short)(uu[q] & 0xFFFF)) * sc_s[c] + sh_s[c];
                    float v1 = bf2f((unsigned short)(uu[q] >> 16)) * sc_s[c + 1] + sh_s[c + 1];
                    oo[q] = pack2(fmaxf(v0, 0.f), fmaxf(v1, 0.f));
                }
                uint4 ov; ov.x = oo[0]; ov.y = oo[1]; ov.z = oo[2]; ov.w = oo[3];
                *(uint4*)&Abuf[s * TM * 32 + srow * 32 + (tid & 3) * 8] = ov;
            }
            if (k0 + 32 * NSUB < K) {   // prefetch next iteration (overlaps MFMA below)
                #pragma unroll
                for (int s = 0; s < NSUB; s++)
                    hvA[s] = *(const uint4*)&A[(size_t)(bm + srow) * K + k0 + 32 * NSUB + 32 * s + skc];
            }
        } else {
            #pragma unroll
            for (int s = 0; s < NSUB; s++)
                #pragma unroll
                for (int c = 0; c < TM / 64; c++) {
                    const unsigned short* ga = A + (size_t)(bm + c * 64 + srow) * K + k0 + 32 * s + skc;
                    char* la = smem + s * TM * 64 + c * 4096 + wv * 1024;
                    __builtin_amdgcn_global_load_lds((gptr_t)ga, (lptr_t)la, 16, 0, 0);
                }
        }
        __syncthreads();
        #pragma unroll
        for (int s = 0; s < NSUB; s++) {
            #pragma unroll
            for (int h = 0; h < 2; h++) {           // two 16-k halves of the 32-k subtile
                int pA = (h * 2 + hi) ^ rsw;        // physical chunk for logical (h,hi)
                bf16x8 af[MI2], bfv[NI2];
                #pragma unroll
                for (int mi = 0; mi < MI2; mi++)
                    af[mi] = *(const bf16x8*)&Abuf[s * TM * 32 + (wm + mi * 32 + m32) * 32 + pA * 8];
                #pragma unroll
                for (int ni = 0; ni < NI2; ni++)
                    bfv[ni] = *(const bf16x8*)&Bbuf[s * TN * 32 + (wn + ni * 32 + m32) * 32 + pA * 8];
                #pragma unroll
                for (int mi = 0; mi < MI2; mi++)
                    #pragma unroll
                    for (int ni = 0; ni < NI2; ni++)
                        acc[mi][ni] = __builtin_amdgcn_mfma_f32_32x32x16_bf16(
                            af[mi], bfv[ni], acc[mi][ni], 0, 0, 0);
            }
        }
        __syncthreads();
    }

    // ---- MODE 0: prefetch epilogue Xbf tiles into VGPRs before the Cst barrier ----
    uint4 xpre[TM / 32];
    if (MODE == 0) {
        #pragma unroll
        for (int ps = 0; ps < TM / 32; ps++) {
            int rl = ps * 32 + (tid >> 3);
            int cl = (tid & 7) * 8;
            xpre[ps] = *(const uint4*)&Xbf[(size_t)(bm + rl) * FD + bn + cl];
        }
    }

    // ---- stats (MODE 1/2), bias folded in; col = wn + ni*32 + m32, 2 lanes/col ----
    if (MODE != 0) {
        #pragma unroll
        for (int ni = 0; ni < NI2; ni++) {
            int col = bn + wn + ni * 32 + m32;
            float bv = (NI2 == 1) ? bvr : bias[col];
            float s = 0.f, ss = 0.f;
            #pragma unroll
            for (int mi = 0; mi < MI2; mi++)
                #pragma unroll
                for (int r = 0; r < 16; r++) {
                    float v = acc[mi][ni][r] + bv;
                    acc[mi][ni][r] = v;
                    s += v; ss += v * v;
                }
            s  += __shfl_xor(s, 32);
            ss += __shfl_xor(ss, 32);
            if (hi == 0) {
                atomicAdd(&sum[col], s);
                atomicAdd(&sumsq[col], ss);
            }
        }
    }

    // ---- stage fp32 C tile to LDS (32x32 C/D layout), then coalesced epilogue ----
    #pragma unroll
    for (int mi = 0; mi < MI2; mi++)
        #pragma unroll
        for (int ni = 0; ni < NI2; ni++) {
            int lcol = wn + ni * 32 + m32;
            #pragma unroll
            for (int r = 0; r < 16; r++) {
                int lrow = wm + mi * 32 + (r & 3) + 8 * (r >> 2) + 4 * hi;
                Cst[lrow * CLD + lcol] = acc[mi][ni][r];
            }
        }
    __syncthreads();
    #pragma unroll
    for (int ps = 0; ps < TM / 32; ps++) {
        int rl = ps * 32 + (tid >> 3);
        int cl = (tid & 7) * 8;
        float4 va = *(const float4*)&Cst[rl * CLD + cl];
        float4 vb = *(const float4*)&Cst[rl * CLD + cl + 4];
        float v[8] = {va.x, va.y, va.z, va.w, vb.x, vb.y, vb.z, vb.w};
        int grow = bm + rl, gcol = bn + cl;
        if (MODE == 0) {
            unsigned int xu[4] = {xpre[ps].x, xpre[ps].y, xpre[ps].z, xpre[ps].w};
            unsigned int oo[4];
            #pragma unroll
            for (int q = 0; q < 4; q++) {
                float x0 = bf2f((unsigned short)(xu[q] & 0xFFFF));
                float x1 = bf2f((unsigned short)(xu[q] >> 16));
                oo[q] = pack2(x0 * v[2 * q], x1 * v[2 * q + 1]);
            }
            uint4 ov; ov.x = oo[0]; ov.y = oo[1]; ov.z = oo[2]; ov.w = oo[3];
            size_t off = (grow < B_SZ)
                ? ((size_t)grow * COMB + gcol)
                : ((size_t)(grow - B_SZ) * COMB + FD + gcol);
            *(uint4*)&Obf[off] = ov;
        } else {
            unsigned int oo[4];
            #pragma unroll
            for (int q = 0; q < 4; q++)
                oo[q] = pack2(v[2 * q], v[2 * q + 1]);
            uint4 ov; ov.x = oo[0]; ov.y = oo[1]; ov.z = oo[2]; ov.w = oo[3];
            *(uint4*)&Obf[(size_t)grow * N + gcol] = ov;
        }
    }
}

// ---------- final: inline finalize1 + dot(w2) + sigmoid; 8 rows/block, 512 blocks ----------
__global__ __launch_bounds__(256) void final_k(const unsigned short* __restrict__ h1,
        const float* __restrict__ sum, const float* __restrict__ sumsq,
        const float* __restrict__ g, const float* __restrict__ be,
        const float* __restrict__ w2, const float* __restrict__ b2,
        const float* __restrict__ lin, const float* __restrict__ bias,
        float* __restrict__ out) {
    __shared__ float sc_s[H1], sh_s[H1], w2_s[H1];
    int t = threadIdx.x;
    int wv = t >> 6, lane = t & 63;
    int r0 = blockIdx.x * 8;
    int c0 = lane * 8;
    // front-load the h1 reads: overlap HBM latency with BN finalize + barrier
    uint4 hvv[2];
    #pragma unroll
    for (int i = 0; i < 2; i++)
        hvv[i] = *(const uint4*)&h1[(size_t)(r0 + wv * 2 + i) * H1 + c0];
    #pragma unroll
    for (int q = 0; q < 2; q++) {
        int c = q * 256 + t;
        float m = sum[c] * (1.f / B_SZ);
        float var = sumsq[c] * (1.f / B_SZ) - m * m;
        float rstd = rsqrtf(var + EPS);
        float sc = g[c] * rstd;
        sc_s[c] = sc;
        sh_s[c] = be[c] - m * sc;
        w2_s[c] = w2[c];
    }
    __syncthreads();
    #pragma unroll
    for (int i = 0; i < 2; i++) {
        int row = r0 + wv * 2 + i;
        unsigned int uu[4] = {hvv[i].x, hvv[i].y, hvv[i].z, hvv[i].w};
        float acc = 0.f;
        #pragma unroll
        for (int q = 0; q < 4; q++) {
            int c = c0 + 2 * q;
            float v0 = bf2f((unsigned short)(uu[q] & 0xFFFF)) * sc_s[c] + sh_s[c];
            float v1 = bf2f((unsigned short)(uu[q] >> 16)) * sc_s[c + 1] + sh_s[c + 1];
            acc += fmaxf(v0, 0.f) * w2_s[c] + fmaxf(v1, 0.f) * w2_s[c + 1];
        }
        #pragma unroll
        for (int off = 32; off > 0; off >>= 1) acc += __shfl_down(acc, off);
        if (lane == 0) {
            float logit = lin[row] + bias[0] + acc + b2[0];
            out[row] = 1.f / (1.f + expf(-logit));
        }
    }
}

extern "C" void kernel_launch(void* const* d_in, const int* in_sizes, int n_in,
                              void* d_out, int out_size, void* d_ws, size_t ws_size,
                              hipStream_t stream) {
    const int*   x    = (const int*)d_in[0];
    const float* emb  = (const float*)d_in[1];
    const float* lint = (const float*)d_in[2];
    const float* bias = (const float*)d_in[3];
    const float* sw1  = (const float*)d_in[4];
    const float* sw2  = (const float*)d_in[5];
    const float* bw   = (const float*)d_in[6];
    const float* w0   = (const float*)d_in[7];
    const float* b0   = (const float*)d_in[8];
    const float* g0   = (const float*)d_in[9];
    const float* be0  = (const float*)d_in[10];
    const float* w1   = (const float*)d_in[11];
    const float* b1   = (const float*)d_in[12];
    const float* g1   = (const float*)d_in[13];
    const float* be1  = (const float*)d_in[14];
    const float* w2   = (const float*)d_in[15];
    const float* b2   = (const float*)d_in[16];
    float* out = (float*)d_out;

    char* p = (char*)d_ws;
    auto alloc = [&](size_t bytes) { char* r = p; p += (bytes + 255) & ~(size_t)255; return r; };

    unsigned short* Xbf  = (unsigned short*)alloc((size_t)2 * B_SZ * FD * 2);
    unsigned short* Wt   = (unsigned short*)alloc((size_t)FD * FD * 2);
    unsigned short* w0t  = (unsigned short*)alloc((size_t)H0 * COMB * 2);
    unsigned short* w1t  = (unsigned short*)alloc((size_t)H1 * H0 * 2);
    unsigned short* Cbf  = (unsigned short*)alloc((size_t)B_SZ * COMB * 2);
    unsigned short* h0bf = (unsigned short*)alloc((size_t)B_SZ * H0 * 2);
    unsigned short* h1bf = (unsigned short*)alloc((size_t)B_SZ * H1 * 2);
    float* lin = (float*)alloc(B_SZ * 4);
    float* sums = (float*)alloc((2 * H0 + 2 * H1) * 4);
    float* sum0 = sums, *sumsq0 = sums + H0, *sum1 = sums + 2 * H0, *sumsq1 = sums + 2 * H0 + H1;

    prep_gather<<<3660, 256, 0, stream>>>(x, emb, lint, sw1, sw2, bw, w0, w1,
                                          Xbf, Wt, w0t, w1t, lin, sums);

    // S = X @ Wt^T, epilogue: Cbf = bf16(X .* S)   [1536 blocks, TM=64, 5/CU LDS cap]
    mfma_gemm<0, FD, FD, 64, 64, 12, 128, 4><<<1536, 256, 0, stream>>>(
        Xbf, Wt, nullptr, Xbf, Cbf, nullptr, nullptr, nullptr, nullptr, nullptr, nullptr);
    // h0 = Cbf @ w0 + b0 (+stats)   [1024 blocks, TM=64, 4/CU]
    mfma_gemm<1, COMB, H0, 64, 64, 16, 64, 4><<<1024, 256, 0, stream>>>(
        Cbf, w0t, b0, nullptr, h0bf, sum0, sumsq0, nullptr, nullptr, nullptr, nullptr);
    // h1 = relu(bn(h0)) @ w1 + b1 (+stats), BN0 fused; BK=256 (4 K-iterations)
    mfma_gemm<2, H0, H1, 64, 64, 8, 64, 8><<<512, 256, 0, stream>>>(
        h0bf, w1t, b1, nullptr, h1bf, sum1, sumsq1, sum0, sumsq0, g0, be0);
    // BN1 finalize + dot + sigmoid fused
    final_k<<<B_SZ / 8, 256, 0, stream>>>(h1bf, sum1, sumsq1, g1, be1,
                                          w2, b2, lin, bias, out);
}

// Round 15
// 157.921 us; speedup vs baseline: 1.0127x; 1.0127x over previous
//
#include <hip/hip_runtime.h>

#define B_SZ 4096
#define F_SZ 24
#define V_SZ 1000
#define D_SZ 32
#define RED  8
#define FD   768      // F*D
#define COMB 1536
#define H0   1024
#define H1   512
#define EPS  1e-5f

typedef __bf16 bf16x8 __attribute__((ext_vector_type(8)));
typedef float  f32x16 __attribute__((ext_vector_type(16)));
typedef const __attribute__((address_space(1))) unsigned int* gptr_t;
typedef       __attribute__((address_space(3))) unsigned int* lptr_t;

__device__ __forceinline__ float bf2f(unsigned short u) {
    union { unsigned int i; float f; } v; v.i = ((unsigned int)u) << 16; return v.f;
}
__device__ __forceinline__ unsigned short f2bf(float f) {
    union { float f; unsigned int i; } v; v.f = f;
    unsigned int u = v.i;
    return (unsigned short)((u + 0x7FFFu + ((u >> 16) & 1u)) >> 16);
}
__device__ __forceinline__ unsigned int pack2(float a, float b) {
    return (unsigned int)f2bf(a) | ((unsigned int)f2bf(b) << 16);
}

// ---------- mega-prep: gather/SENet + Wt reorder (vec4) + w0/w1 transpose + zero sums ----------
__global__ __launch_bounds__(256) void prep_gather(
        const int* __restrict__ x, const float* __restrict__ emb,
        const float* __restrict__ lint, const float* __restrict__ sw1,
        const float* __restrict__ sw2, const float* __restrict__ bw,
        const float* __restrict__ w0, const float* __restrict__ w1,
        unsigned short* __restrict__ Xbf, unsigned short* __restrict__ Wt,
        unsigned short* __restrict__ w0t, unsigned short* __restrict__ w1t,
        float* __restrict__ lin, float* __restrict__ sums) {
    int bid = blockIdx.x;
    int tid = threadIdx.x;
    if (bid < 1024) {
        int w = tid >> 6, lane = tid & 63;
        int b = bid * 4 + w;
        __shared__ int   xi[4][F_SZ];
        __shared__ float e[4][F_SZ][D_SZ];
        __shared__ float Z[4][F_SZ];
        __shared__ float r1[4][RED];
        __shared__ float Afac[4][F_SZ];
        if (lane < F_SZ) xi[w][lane] = x[b * F_SZ + lane];
        __syncthreads();
        #pragma unroll
        for (int it = 0; it < 3; it++) {
            int idx = it * 64 + lane;
            int f = idx >> 3, k4 = (idx & 7) * 4;
            float4 v = *(const float4*)&emb[((size_t)f * V_SZ + xi[w][f]) * D_SZ + k4];
            *(float4*)&e[w][f][k4] = v;
        }
        __syncthreads();
        if (lane < F_SZ) {
            float s = 0.f;
            #pragma unroll
            for (int k = 0; k < D_SZ; k++) s += e[w][lane][k];
            Z[w][lane] = s * (1.f / D_SZ);
        }
        __syncthreads();
        if (lane < RED) {
            float s = 0.f;
            #pragma unroll
            for (int f = 0; f < F_SZ; f++) s += Z[w][f] * sw1[lane * F_SZ + f];
            r1[w][lane] = fmaxf(s, 0.f);
        }
        __syncthreads();
        if (lane < F_SZ) {
            float s = 0.f;
            #pragma unroll
            for (int r = 0; r < RED; r++) s += r1[w][r] * sw2[lane * RED + r];
            Afac[w][lane] = 1.f / (1.f + expf(-s));
        }
        __syncthreads();
        #pragma unroll
        for (int it = 0; it < 3; it++) {
            int idx = it * 64 + lane;
            int f = idx >> 3, k4 = (idx & 7) * 4;
            const float* p = &e[w][f][k4];
            uint2 u, us;
            u.x = pack2(p[0], p[1]); u.y = pack2(p[2], p[3]);
            float a = Afac[w][f];
            us.x = pack2(p[0] * a, p[1] * a); us.y = pack2(p[2] * a, p[3] * a);
            *(uint2*)&Xbf[(size_t)b * FD + idx * 4] = u;
            *(uint2*)&Xbf[(size_t)(B_SZ + b) * FD + idx * 4] = us;
        }
        float lv = (lane < F_SZ) ? lint[lane * V_SZ + xi[w][lane]] : 0.f;
        #pragma unroll
        for (int off = 32; off > 0; off >>= 1) lv += __shfl_down(lv, off);
        if (lane == 0) lin[b] = lv;
    } else if (bid < 1600) {
        // Wt reorder, 4 elems/thread: all 4 share (i,j,k) run since 768%4==0
        int o4 = ((bid - 1024) * 256 + tid) * 4;
        int ik = o4 / FD, jl = o4 - ik * FD;
        int i = ik >> 5, k = ik & 31, j = jl >> 5, l = jl & 31;
        uint2 ov;
        if (i == j) {
            ov.x = 0u; ov.y = 0u;
        } else {
            float4 v = *(const float4*)&bw[(((size_t)i * F_SZ + j) * D_SZ + k) * D_SZ + l];
            ov.x = pack2(v.x, v.y); ov.y = pack2(v.z, v.w);
        }
        *(uint2*)&Wt[o4] = ov;
    } else if (bid < 3648) {
        __shared__ float tile[32][33];
        const float* in; unsigned short* out; int K, N, bx, by;
        if (bid < 3136) { int t = bid - 1600; in = w0; out = w0t; K = COMB; N = H0; bx = t & 31; by = t >> 5; }
        else            { int t = bid - 3136; in = w1; out = w1t; K = H0;   N = H1; bx = t & 15; by = t >> 4; }
        int tx = tid & 31, ty = tid >> 5;
        int n0 = bx * 32, k0 = by * 32;
        #pragma unroll
        for (int r = 0; r < 32; r += 8)
            tile[ty + r][tx] = in[(size_t)(k0 + ty + r) * N + n0 + tx];
        __syncthreads();
        #pragma unroll
        for (int r = 0; r < 32; r += 8)
            out[(size_t)(n0 + ty + r) * K + k0 + tx] = f2bf(tile[tx][ty + r]);
    } else {
        int o = (bid - 3648) * 256 + tid;   // 3072 floats
        sums[o] = 0.f;
    }
}

// ---------- MFMA GEMM: C = A[M,K](bf16) @ Bt[N,K]^T(bf16), TMxTN tile, BK=32*NSUB ----------
// 32x32x16 MFMA microtiles; LDS 16B-chunk XOR swizzle keeps global_load_lds lane-contiguity.
// MODE 0: C = Xbf .* S -> Obf[4096,1536] (epilogue Xbf prefetched before Cst barrier).
// MODE 1: +bias, bf16 store, fused BN stats. MODE 2: A = relu(bn(Araw)) via prefetched VGPRs.
// All latency chains front-loaded: bias pre-K-loop, MODE2 first-A before sc_s barrier.
template<int MODE, int K, int N, int TM, int TN, int GX, int GY, int NSUB>
__global__ __launch_bounds__(256) void mfma_gemm(
        const unsigned short* __restrict__ A,
        const unsigned short* __restrict__ Bt,
        const float* __restrict__ bias,
        const unsigned short* __restrict__ Xbf,
        unsigned short* __restrict__ Obf,
        float* __restrict__ sum, float* __restrict__ sumsq,
        const float* __restrict__ psum, const float* __restrict__ psumsq,
        const float* __restrict__ g, const float* __restrict__ be) {
    constexpr int MI2 = TM / 64, NI2 = TN / 64;       // 32x32 tiles per wave
    constexpr int CLD = TN + 4;                       // padded fp32 C stride
    constexpr int STAGE = (TM + TN) * NSUB * 64;      // bytes: 32*NSUB kcols x 2B
    constexpr int CST   = TM * CLD * 4;
    constexpr int SMEM  = STAGE > CST ? STAGE : CST;
    __shared__ __align__(16) char smem[SMEM];
    unsigned short* Abuf = (unsigned short*)smem;                      // [NSUB][TM*32]
    unsigned short* Bbuf = (unsigned short*)(smem + TM * NSUB * 64);   // [NSUB][TN*32]
    float* Cst = (float*)smem;
    __shared__ float sc_s[MODE == 2 ? K : 1];
    __shared__ float sh_s[MODE == 2 ? K : 1];
    const int tid  = threadIdx.x;
    const int lane = tid & 63, wv = tid >> 6;
    const int wm = (wv >> 1) * (TM / 2), wn = (wv & 1) * (TN / 2);
    const int m32 = lane & 31, hi = lane >> 5;        // 32x32 frag coords
    const int rsw = (m32 >> 1) & 3;                   // read-side swizzle key
    const int bid = blockIdx.x;
    const int xcd = bid & 7, slot = bid >> 3;
    const int rowb = xcd * (GY / 8) + slot / GX;
    const int colb = slot % GX;
    const int bm = rowb * TM, bn = colb * TN;
    const int srow = tid >> 2;                        // 0..63
    const int skc  = (((tid & 3) ^ ((tid >> 3) & 3)) * 8);  // swizzled k-offset (shorts)

    // front-loaded independent loads: first A panel (MODE 2) + bias scalar
    uint4 hvA[NSUB];
    if (MODE == 2) {
        #pragma unroll
        for (int s = 0; s < NSUB; s++)
            hvA[s] = *(const uint4*)&A[(size_t)(bm + srow) * K + 32 * s + skc];
    }
    float bvr = 0.f;
    if (MODE != 0) bvr = bias[bn + wn + m32];

    if (MODE == 2) {
        #pragma unroll
        for (int q = 0; q < K / 256; q++) {
            int c = q * 256 + tid;
            float m = psum[c] * (1.f / B_SZ);
            float var = psumsq[c] * (1.f / B_SZ) - m * m;
            float rstd = rsqrtf(var + EPS);
            float sc = g[c] * rstd;
            sc_s[c] = sc;
            sh_s[c] = be[c] - m * sc;
        }
        __syncthreads();
    }

    f32x16 acc[MI2][NI2];
    #pragma unroll
    for (int i = 0; i < MI2; i++)
        #pragma unroll
        for (int j = 0; j < NI2; j++)
            #pragma unroll
            for (int r = 0; r < 16; r++) acc[i][j][r] = 0.f;

    for (int k0 = 0; k0 < K; k0 += 32 * NSUB) {
        // B DMA first: overlaps MODE 2's A VALU processing below
        #pragma unroll
        for (int s = 0; s < NSUB; s++)
            #pragma unroll
            for (int c = 0; c < TN / 64; c++) {
                const unsigned short* gb = Bt + (size_t)(bn + c * 64 + srow) * K + k0 + 32 * s + skc;
                char* lb = smem + TM * NSUB * 64 + s * TN * 64 + c * 4096 + wv * 1024;
                __builtin_amdgcn_global_load_lds((gptr_t)gb, (lptr_t)lb, 16, 0, 0);
            }
        if (MODE == 2) {
            #pragma unroll
            for (int s = 0; s < NSUB; s++) {
                unsigned int uu[4] = {hvA[s].x, hvA[s].y, hvA[s].z, hvA[s].w};
                unsigned int oo[4];
                #pragma unroll
                for (int q = 0; q < 4; q++) {
                    int c = k0 + 32 * s + skc + 2 * q;
                    float v0 = bf2f((unsigned short)(uu[q] & 0xFFFF)) * sc_s[c] + sh_s[c];
                    float v1 = bf2f((unsigned short)(uu[q] >> 16)) * sc_s[c + 1] + sh_s[c + 1];
                    oo[q] = pack2(fmaxf(v0, 0.f), fmaxf(v1, 0.f));
                }
                uint4 ov; ov.x = oo[0]; ov.y = oo[1]; ov.z = oo[2]; ov.w = oo[3];
                *(uint4*)&Abuf[s * TM * 32 + srow * 32 + (tid & 3) * 8] = ov;
            }
            if (k0 + 32 * NSUB < K) {   // prefetch next iteration (overlaps MFMA below)
                #pragma unroll
                for (int s = 0; s < NSUB; s++)
                    hvA[s] = *(const uint4*)&A[(size_t)(bm + srow) * K + k0 + 32 * NSUB + 32 * s + skc];
            }
        } else {
            #pragma unroll
            for (int s = 0; s < NSUB; s++)
                #pragma unroll
                for (int c = 0; c < TM / 64; c++) {
                    const unsigned short* ga = A + (size_t)(bm + c * 64 + srow) * K + k0 + 32 * s + skc;
                    char* la = smem + s * TM * 64 + c * 4096 + wv * 1024;
                    __builtin_amdgcn_global_load_lds((gptr_t)ga, (lptr_t)la, 16, 0, 0);
                }
        }
        __syncthreads();
        #pragma unroll
        for (int s = 0; s < NSUB; s++) {
            #pragma unroll
            for (int h = 0; h < 2; h++) {           // two 16-k halves of the 32-k subtile
                int pA = (h * 2 + hi) ^ rsw;        // physical chunk for logical (h,hi)
                bf16x8 af[MI2], bfv[NI2];
                #pragma unroll
                for (int mi = 0; mi < MI2; mi++)
                    af[mi] = *(const bf16x8*)&Abuf[s * TM * 32 + (wm + mi * 32 + m32) * 32 + pA * 8];
                #pragma unroll
                for (int ni = 0; ni < NI2; ni++)
                    bfv[ni] = *(const bf16x8*)&Bbuf[s * TN * 32 + (wn + ni * 32 + m32) * 32 + pA * 8];
                #pragma unroll
                for (int mi = 0; mi < MI2; mi++)
                    #pragma unroll
                    for (int ni = 0; ni < NI2; ni++)
                        acc[mi][ni] = __builtin_amdgcn_mfma_f32_32x32x16_bf16(
                            af[mi], bfv[ni], acc[mi][ni], 0, 0, 0);
            }
        }
        __syncthreads();
    }

    // ---- MODE 0: prefetch epilogue Xbf tiles into VGPRs before the Cst barrier ----
    uint4 xpre[TM / 32];
    if (MODE == 0) {
        #pragma unroll
        for (int ps = 0; ps < TM / 32; ps++) {
            int rl = ps * 32 + (tid >> 3);
            int cl = (tid & 7) * 8;
            xpre[ps] = *(const uint4*)&Xbf[(size_t)(bm + rl) * FD + bn + cl];
        }
    }

    // ---- stats (MODE 1/2), bias folded in; col = wn + ni*32 + m32, 2 lanes/col ----
    if (MODE != 0) {
        #pragma unroll
        for (int ni = 0; ni < NI2; ni++) {
            int col = bn + wn + ni * 32 + m32;
            float bv = (NI2 == 1) ? bvr : bias[col];
            float s = 0.f, ss = 0.f;
            #pragma unroll
            for (int mi = 0; mi < MI2; mi++)
                #pragma unroll
                for (int r = 0; r < 16; r++) {
                    float v = acc[mi][ni][r] + bv;
                    acc[mi][ni][r] = v;
                    s += v; ss += v * v;
                }
            s  += __shfl_xor(s, 32);
            ss += __shfl_xor(ss, 32);
            if (hi == 0) {
                atomicAdd(&sum[col], s);
                atomicAdd(&sumsq[col], ss);
            }
        }
    }

    // ---- stage fp32 C tile to LDS (32x32 C/D layout), then coalesced epilogue ----
    #pragma unroll
    for (int mi = 0; mi < MI2; mi++)
        #pragma unroll
        for (int ni = 0; ni < NI2; ni++) {
            int lcol = wn + ni * 32 + m32;
            #pragma unroll
            for (int r = 0; r < 16; r++) {
                int lrow = wm + mi * 32 + (r & 3) + 8 * (r >> 2) + 4 * hi;
                Cst[lrow * CLD + lcol] = acc[mi][ni][r];
            }
        }
    __syncthreads();
    #pragma unroll
    for (int ps = 0; ps < TM / 32; ps++) {
        int rl = ps * 32 + (tid >> 3);
        int cl = (tid & 7) * 8;
        float4 va = *(const float4*)&Cst[rl * CLD + cl];
        float4 vb = *(const float4*)&Cst[rl * CLD + cl + 4];
        float v[8] = {va.x, va.y, va.z, va.w, vb.x, vb.y, vb.z, vb.w};
        int grow = bm + rl, gcol = bn + cl;
        if (MODE == 0) {
            unsigned int xu[4] = {xpre[ps].x, xpre[ps].y, xpre[ps].z, xpre[ps].w};
            unsigned int oo[4];
            #pragma unroll
            for (int q = 0; q < 4; q++) {
                float x0 = bf2f((unsigned short)(xu[q] & 0xFFFF));
                float x1 = bf2f((unsigned short)(xu[q] >> 16));
                oo[q] = pack2(x0 * v[2 * q], x1 * v[2 * q + 1]);
            }
            uint4 ov; ov.x = oo[0]; ov.y = oo[1]; ov.z = oo[2]; ov.w = oo[3];
            size_t off = (grow < B_SZ)
                ? ((size_t)grow * COMB + gcol)
                : ((size_t)(grow - B_SZ) * COMB + FD + gcol);
            *(uint4*)&Obf[off] = ov;
        } else {
            unsigned int oo[4];
            #pragma unroll
            for (int q = 0; q < 4; q++)
                oo[q] = pack2(v[2 * q], v[2 * q + 1]);
            uint4 ov; ov.x = oo[0]; ov.y = oo[1]; ov.z = oo[2]; ov.w = oo[3];
            *(uint4*)&Obf[(size_t)grow * N + gcol] = ov;
        }
    }
}

// ---------- final: inline finalize1 + dot(w2) + sigmoid; 8 rows/block, 512 blocks ----------
__global__ __launch_bounds__(256) void final_k(const unsigned short* __restrict__ h1,
        const float* __restrict__ sum, const float* __restrict__ sumsq,
        const float* __restrict__ g, const float* __restrict__ be,
        const float* __restrict__ w2, const float* __restrict__ b2,
        const float* __restrict__ lin, const float* __restrict__ bias,
        float* __restrict__ out) {
    __shared__ float sc_s[H1], sh_s[H1], w2_s[H1];
    int t = threadIdx.x;
    int wv = t >> 6, lane = t & 63;
    int r0 = blockIdx.x * 8;
    int c0 = lane * 8;
    // front-load the h1 reads: overlap HBM latency with BN finalize + barrier
    uint4 hvv[2];
    #pragma unroll
    for (int i = 0; i < 2; i++)
        hvv[i] = *(const uint4*)&h1[(size_t)(r0 + wv * 2 + i) * H1 + c0];
    #pragma unroll
    for (int q = 0; q < 2; q++) {
        int c = q * 256 + t;
        float m = sum[c] * (1.f / B_SZ);
        float var = sumsq[c] * (1.f / B_SZ) - m * m;
        float rstd = rsqrtf(var + EPS);
        float sc = g[c] * rstd;
        sc_s[c] = sc;
        sh_s[c] = be[c] - m * sc;
        w2_s[c] = w2[c];
    }
    __syncthreads();
    #pragma unroll
    for (int i = 0; i < 2; i++) {
        int row = r0 + wv * 2 + i;
        unsigned int uu[4] = {hvv[i].x, hvv[i].y, hvv[i].z, hvv[i].w};
        float acc = 0.f;
        #pragma unroll
        for (int q = 0; q < 4; q++) {
            int c = c0 + 2 * q;
            float v0 = bf2f((unsigned short)(uu[q] & 0xFFFF)) * sc_s[c] + sh_s[c];
            float v1 = bf2f((unsigned short)(uu[q] >> 16)) * sc_s[c + 1] + sh_s[c + 1];
            acc += fmaxf(v0, 0.f) * w2_s[c] + fmaxf(v1, 0.f) * w2_s[c + 1];
        }
        #pragma unroll
        for (int off = 32; off > 0; off >>= 1) acc += __shfl_down(acc, off);
        if (lane == 0) {
            float logit = lin[row] + bias[0] + acc + b2[0];
            out[row] = 1.f / (1.f + expf(-logit));
        }
    }
}

extern "C" void kernel_launch(void* const* d_in, const int* in_sizes, int n_in,
                              void* d_out, int out_size, void* d_ws, size_t ws_size,
                              hipStream_t stream) {
    const int*   x    = (const int*)d_in[0];
    const float* emb  = (const float*)d_in[1];
    const float* lint = (const float*)d_in[2];
    const float* bias = (const float*)d_in[3];
    const float* sw1  = (const float*)d_in[4];
    const float* sw2  = (const float*)d_in[5];
    const float* bw   = (const float*)d_in[6];
    const float* w0   = (const float*)d_in[7];
    const float* b0   = (const float*)d_in[8];
    const float* g0   = (const float*)d_in[9];
    const float* be0  = (const float*)d_in[10];
    const float* w1   = (const float*)d_in[11];
    const float* b1   = (const float*)d_in[12];
    const float* g1   = (const float*)d_in[13];
    const float* be1  = (const float*)d_in[14];
    const float* w2   = (const float*)d_in[15];
    const float* b2   = (const float*)d_in[16];
    float* out = (float*)d_out;

    char* p = (char*)d_ws;
    auto alloc = [&](size_t bytes) { char* r = p; p += (bytes + 255) & ~(size_t)255; return r; };

    unsigned short* Xbf  = (unsigned short*)alloc((size_t)2 * B_SZ * FD * 2);
    unsigned short* Wt   = (unsigned short*)alloc((size_t)FD * FD * 2);
    unsigned short* w0t  = (unsigned short*)alloc((size_t)H0 * COMB * 2);
    unsigned short* w1t  = (unsigned short*)alloc((size_t)H1 * H0 * 2);
    unsigned short* Cbf  = (unsigned short*)alloc((size_t)B_SZ * COMB * 2);
    unsigned short* h0bf = (unsigned short*)alloc((size_t)B_SZ * H0 * 2);
    unsigned short* h1bf = (unsigned short*)alloc((size_t)B_SZ * H1 * 2);
    float* lin = (float*)alloc(B_SZ * 4);
    float* sums = (float*)alloc((2 * H0 + 2 * H1) * 4);
    float* sum0 = sums, *sumsq0 = sums + H0, *sum1 = sums + 2 * H0, *sumsq1 = sums + 2 * H0 + H1;

    prep_gather<<<3660, 256, 0, stream>>>(x, emb, lint, sw1, sw2, bw, w0, w1,
                                          Xbf, Wt, w0t, w1t, lin, sums);

    // S = X @ Wt^T, epilogue: Cbf = bf16(X .* S)   [768 blocks, TM=128, 3/CU]
    mfma_gemm<0, FD, FD, 128, 64, 12, 64, 4><<<768, 256, 0, stream>>>(
        Xbf, Wt, nullptr, Xbf, Cbf, nullptr, nullptr, nullptr, nullptr, nullptr, nullptr);
    // h0 = Cbf @ w0 + b0 (+stats)   [512 blocks, TM=128, BK=192 -> 8 K-iterations, 2/CU]
    mfma_gemm<1, COMB, H0, 128, 64, 16, 32, 6><<<512, 256, 0, stream>>>(
        Cbf, w0t, b0, nullptr, h0bf, sum0, sumsq0, nullptr, nullptr, nullptr, nullptr);
    // h1 = relu(bn(h0)) @ w1 + b1 (+stats), BN0 fused; BK=256 (4 K-iterations)
    mfma_gemm<2, H0, H1, 64, 64, 8, 64, 8><<<512, 256, 0, stream>>>(
        h0bf, w1t, b1, nullptr, h1bf, sum1, sumsq1, sum0, sumsq0, g0, be0);
    // BN1 finalize + dot + sigmoid fused
    final_k<<<B_SZ / 8, 256, 0, stream>>>(h1bf, sum1, sumsq1, g1, be1,
                                          w2, b2, lin, bias, out);
}

// Round 17
// 155.739 us; speedup vs baseline: 1.0269x; 1.0140x over previous
//
#include <hip/hip_runtime.h>

#define B_SZ 4096
#define F_SZ 24
#define V_SZ 1000
#define D_SZ 32
#define RED  8
#define FD   768      // F*D
#define COMB 1536
#define H0   1024
#define H1   512
#define EPS  1e-5f

typedef __bf16 bf16x8 __attribute__((ext_vector_type(8)));
typedef float  f32x16 __attribute__((ext_vector_type(16)));
typedef const __attribute__((address_space(1))) unsigned int* gptr_t;
typedef       __attribute__((address_space(3))) unsigned int* lptr_t;

__device__ __forceinline__ float bf2f(unsigned short u) {
    union { unsigned int i; float f; } v; v.i = ((unsigned int)u) << 16; return v.f;
}
__device__ __forceinline__ unsigned short f2bf(float f) {
    union { float f; unsigned int i; } v; v.f = f;
    unsigned int u = v.i;
    return (unsigned short)((u + 0x7FFFu + ((u >> 16) & 1u)) >> 16);
}
__device__ __forceinline__ unsigned int pack2(float a, float b) {
    return (unsigned int)f2bf(a) | ((unsigned int)f2bf(b) << 16);
}

// ---------- mega-prep: Wt reorder + w0/w1 transpose + gather/SENet + zero sums ----------
__global__ __launch_bounds__(256) void prep_gather(
        const int* __restrict__ x, const float* __restrict__ emb,
        const float* __restrict__ lint, const float* __restrict__ sw1,
        const float* __restrict__ sw2, const float* __restrict__ bw,
        const float* __restrict__ w0, const float* __restrict__ w1,
        unsigned short* __restrict__ Xbf, unsigned short* __restrict__ Wt,
        unsigned short* __restrict__ w0t, unsigned short* __restrict__ w1t,
        float* __restrict__ lin, float* __restrict__ sums) {
    int bid = blockIdx.x;
    int tid = threadIdx.x;
    if (bid < 1024) {
        int w = tid >> 6, lane = tid & 63;
        int b = bid * 4 + w;
        __shared__ int   xi[4][F_SZ];
        __shared__ float e[4][F_SZ][D_SZ];
        __shared__ float Z[4][F_SZ];
        __shared__ float r1[4][RED];
        __shared__ float Afac[4][F_SZ];
        if (lane < F_SZ) xi[w][lane] = x[b * F_SZ + lane];
        __syncthreads();
        #pragma unroll
        for (int it = 0; it < 3; it++) {
            int idx = it * 64 + lane;
            int f = idx >> 3, k4 = (idx & 7) * 4;
            float4 v = *(const float4*)&emb[((size_t)f * V_SZ + xi[w][f]) * D_SZ + k4];
            *(float4*)&e[w][f][k4] = v;
        }
        __syncthreads();
        if (lane < F_SZ) {
            float s = 0.f;
            #pragma unroll
            for (int k = 0; k < D_SZ; k++) s += e[w][lane][k];
            Z[w][lane] = s * (1.f / D_SZ);
        }
        __syncthreads();
        if (lane < RED) {
            float s = 0.f;
            #pragma unroll
            for (int f = 0; f < F_SZ; f++) s += Z[w][f] * sw1[lane * F_SZ + f];
            r1[w][lane] = fmaxf(s, 0.f);
        }
        __syncthreads();
        if (lane < F_SZ) {
            float s = 0.f;
            #pragma unroll
            for (int r = 0; r < RED; r++) s += r1[w][r] * sw2[lane * RED + r];
            Afac[w][lane] = 1.f / (1.f + expf(-s));
        }
        __syncthreads();
        #pragma unroll
        for (int it = 0; it < 3; it++) {
            int idx = it * 64 + lane;
            int f = idx >> 3, k4 = (idx & 7) * 4;
            const float* p = &e[w][f][k4];
            uint2 u, us;
            u.x = pack2(p[0], p[1]); u.y = pack2(p[2], p[3]);
            float a = Afac[w][f];
            us.x = pack2(p[0] * a, p[1] * a); us.y = pack2(p[2] * a, p[3] * a);
            *(uint2*)&Xbf[(size_t)b * FD + idx * 4] = u;
            *(uint2*)&Xbf[(size_t)(B_SZ + b) * FD + idx * 4] = us;
        }
        float lv = (lane < F_SZ) ? lint[lane * V_SZ + xi[w][lane]] : 0.f;
        #pragma unroll
        for (int off = 32; off > 0; off >>= 1) lv += __shfl_down(lv, off);
        if (lane == 0) lin[b] = lv;
    } else if (bid < 3328) {
        int o = (bid - 1024) * 256 + tid;
        int ik = o / FD, jl = o - ik * FD;
        int i = ik >> 5, k = ik & 31, j = jl >> 5, l = jl & 31;
        Wt[o] = (i == j) ? (unsigned short)0
                         : f2bf(bw[(((size_t)i * F_SZ + j) * D_SZ + k) * D_SZ + l]);
    } else if (bid < 5376) {
        __shared__ float tile[32][33];
        const float* in; unsigned short* out; int K, N, bx, by;
        if (bid < 4864) { int t = bid - 3328; in = w0; out = w0t; K = COMB; N = H0; bx = t & 31; by = t >> 5; }
        else            { int t = bid - 4864; in = w1; out = w1t; K = H0;   N = H1; bx = t & 15; by = t >> 4; }
        int tx = tid & 31, ty = tid >> 5;
        int n0 = bx * 32, k0 = by * 32;
        #pragma unroll
        for (int r = 0; r < 32; r += 8)
            tile[ty + r][tx] = in[(size_t)(k0 + ty + r) * N + n0 + tx];
        __syncthreads();
        #pragma unroll
        for (int r = 0; r < 32; r += 8)
            out[(size_t)(n0 + ty + r) * K + k0 + tx] = f2bf(tile[tx][ty + r]);
    } else {
        int o = (bid - 5376) * 256 + tid;   // 3072 floats
        sums[o] = 0.f;
    }
}

// ---------- MFMA GEMM: C = A[M,K](bf16) @ Bt[N,K]^T(bf16), TMxTN tile, BK=32*NSUB ----------
// 32x32x16 MFMA microtiles; LDS 16B-chunk XOR swizzle keeps global_load_lds lane-contiguity.
// MODE 0: C = Xbf .* S -> Obf[4096,1536] (epilogue Xbf prefetched before Cst barrier).
// MODE 1: +bias, bf16 store, fused BN stats. MODE 2: A = relu(bn(Araw)) via prefetched VGPRs.
// All latency chains front-loaded: bias pre-K-loop, MODE2 first-A before sc_s barrier.
template<int MODE, int K, int N, int TM, int TN, int GX, int GY, int NSUB>
__global__ __launch_bounds__(256) void mfma_gemm(
        const unsigned short* __restrict__ A,
        const unsigned short* __restrict__ Bt,
        const float* __restrict__ bias,
        const unsigned short* __restrict__ Xbf,
        unsigned short* __restrict__ Obf,
        float* __restrict__ sum, float* __restrict__ sumsq,
        const float* __restrict__ psum, const float* __restrict__ psumsq,
        const float* __restrict__ g, const float* __restrict__ be) {
    constexpr int MI2 = TM / 64, NI2 = TN / 64;       // 32x32 tiles per wave
    constexpr int CLD = TN + 4;                       // padded fp32 C stride
    constexpr int STAGE = (TM + TN) * NSUB * 64;      // bytes: 32*NSUB kcols x 2B
    constexpr int CST   = TM * CLD * 4;
    constexpr int SMEM  = STAGE > CST ? STAGE : CST;
    __shared__ __align__(16) char smem[SMEM];
    unsigned short* Abuf = (unsigned short*)smem;                      // [NSUB][TM*32]
    unsigned short* Bbuf = (unsigned short*)(smem + TM * NSUB * 64);   // [NSUB][TN*32]
    float* Cst = (float*)smem;
    __shared__ float sc_s[MODE == 2 ? K : 1];
    __shared__ float sh_s[MODE == 2 ? K : 1];
    const int tid  = threadIdx.x;
    const int lane = tid & 63, wv = tid >> 6;
    const int wm = (wv >> 1) * (TM / 2), wn = (wv & 1) * (TN / 2);
    const int m32 = lane & 31, hi = lane >> 5;        // 32x32 frag coords
    const int rsw = (m32 >> 1) & 3;                   // read-side swizzle key
    const int bid = blockIdx.x;
    const int xcd = bid & 7, slot = bid >> 3;
    const int rowb = xcd * (GY / 8) + slot / GX;
    const int colb = slot % GX;
    const int bm = rowb * TM, bn = colb * TN;
    const int srow = tid >> 2;                        // 0..63
    const int skc  = (((tid & 3) ^ ((tid >> 3) & 3)) * 8);  // swizzled k-offset (shorts)

    // front-loaded independent loads: first A panel (MODE 2) + bias scalar
    uint4 hvA[NSUB];
    if (MODE == 2) {
        #pragma unroll
        for (int s = 0; s < NSUB; s++)
            hvA[s] = *(const uint4*)&A[(size_t)(bm + srow) * K + 32 * s + skc];
    }
    float bvr = 0.f;
    if (MODE != 0) bvr = bias[bn + wn + m32];

    if (MODE == 2) {
        #pragma unroll
        for (int q = 0; q < K / 256; q++) {
            int c = q * 256 + tid;
            float m = psum[c] * (1.f / B_SZ);
            float var = psumsq[c] * (1.f / B_SZ) - m * m;
            float rstd = rsqrtf(var + EPS);
            float sc = g[c] * rstd;
            sc_s[c] = sc;
            sh_s[c] = be[c] - m * sc;
        }
        __syncthreads();
    }

    f32x16 acc[MI2][NI2];
    #pragma unroll
    for (int i = 0; i < MI2; i++)
        #pragma unroll
        for (int j = 0; j < NI2; j++)
            #pragma unroll
            for (int r = 0; r < 16; r++) acc[i][j][r] = 0.f;

    for (int k0 = 0; k0 < K; k0 += 32 * NSUB) {
        // B DMA first: overlaps MODE 2's A VALU processing below
        #pragma unroll
        for (int s = 0; s < NSUB; s++)
            #pragma unroll
            for (int c = 0; c < TN / 64; c++) {
                const unsigned short* gb = Bt + (size_t)(bn + c * 64 + srow) * K + k0 + 32 * s + skc;
                char* lb = smem + TM * NSUB * 64 + s * TN * 64 + c * 4096 + wv * 1024;
                __builtin_amdgcn_global_load_lds((gptr_t)gb, (lptr_t)lb, 16, 0, 0);
            }
        if (MODE == 2) {
            #pragma unroll
            for (int s = 0; s < NSUB; s++) {
                unsigned int uu[4] = {hvA[s].x, hvA[s].y, hvA[s].z, hvA[s].w};
                unsigned int oo[4];
                #pragma unroll
                for (int q = 0; q < 4; q++) {
                    int c = k0 + 32 * s + skc + 2 * q;
                    float v0 = bf2f((unsigned short)(uu[q] & 0xFFFF)) * sc_s[c] + sh_s[c];
                    float v1 = bf2f((unsigned short)(uu[q] >> 16)) * sc_s[c + 1] + sh_s[c + 1];
                    oo[q] = pack2(fmaxf(v0, 0.f), fmaxf(v1, 0.f));
                }
                uint4 ov; ov.x = oo[0]; ov.y = oo[1]; ov.z = oo[2]; ov.w = oo[3];
                *(uint4*)&Abuf[s * TM * 32 + srow * 32 + (tid & 3) * 8] = ov;
            }
            if (k0 + 32 * NSUB < K) {   // prefetch next iteration (overlaps MFMA below)
                #pragma unroll
                for (int s = 0; s < NSUB; s++)
                    hvA[s] = *(const uint4*)&A[(size_t)(bm + srow) * K + k0 + 32 * NSUB + 32 * s + skc];
            }
        } else {
            #pragma unroll
            for (int s = 0; s < NSUB; s++)
                #pragma unroll
                for (int c = 0; c < TM / 64; c++) {
                    const unsigned short* ga = A + (size_t)(bm + c * 64 + srow) * K + k0 + 32 * s + skc;
                    char* la = smem + s * TM * 64 + c * 4096 + wv * 1024;
                    __builtin_amdgcn_global_load_lds((gptr_t)ga, (lptr_t)la, 16, 0, 0);
                }
        }
        __syncthreads();
        #pragma unroll
        for (int s = 0; s < NSUB; s++) {
            #pragma unroll
            for (int h = 0; h < 2; h++) {           // two 16-k halves of the 32-k subtile
                int pA = (h * 2 + hi) ^ rsw;        // physical chunk for logical (h,hi)
                bf16x8 af[MI2], bfv[NI2];
                #pragma unroll
                for (int mi = 0; mi < MI2; mi++)
                    af[mi] = *(const bf16x8*)&Abuf[s * TM * 32 + (wm + mi * 32 + m32) * 32 + pA * 8];
                #pragma unroll
                for (int ni = 0; ni < NI2; ni++)
                    bfv[ni] = *(const bf16x8*)&Bbuf[s * TN * 32 + (wn + ni * 32 + m32) * 32 + pA * 8];
                #pragma unroll
                for (int mi = 0; mi < MI2; mi++)
                    #pragma unroll
                    for (int ni = 0; ni < NI2; ni++)
                        acc[mi][ni] = __builtin_amdgcn_mfma_f32_32x32x16_bf16(
                            af[mi], bfv[ni], acc[mi][ni], 0, 0, 0);
            }
        }
        __syncthreads();
    }

    // ---- MODE 0: prefetch epilogue Xbf tiles into VGPRs before the Cst barrier ----
    uint4 xpre[TM / 32];
    if (MODE == 0) {
        #pragma unroll
        for (int ps = 0; ps < TM / 32; ps++) {
            int rl = ps * 32 + (tid >> 3);
            int cl = (tid & 7) * 8;
            xpre[ps] = *(const uint4*)&Xbf[(size_t)(bm + rl) * FD + bn + cl];
        }
    }

    // ---- stats (MODE 1/2), bias folded in; col = wn + ni*32 + m32, 2 lanes/col ----
    if (MODE != 0) {
        #pragma unroll
        for (int ni = 0; ni < NI2; ni++) {
            int col = bn + wn + ni * 32 + m32;
            float bv = (NI2 == 1) ? bvr : bias[col];
            float s = 0.f, ss = 0.f;
            #pragma unroll
            for (int mi = 0; mi < MI2; mi++)
                #pragma unroll
                for (int r = 0; r < 16; r++) {
                    float v = acc[mi][ni][r] + bv;
                    acc[mi][ni][r] = v;
                    s += v; ss += v * v;
                }
            s  += __shfl_xor(s, 32);
            ss += __shfl_xor(ss, 32);
            if (hi == 0) {
                atomicAdd(&sum[col], s);
                atomicAdd(&sumsq[col], ss);
            }
        }
    }

    // ---- stage fp32 C tile to LDS (32x32 C/D layout), then coalesced epilogue ----
    #pragma unroll
    for (int mi = 0; mi < MI2; mi++)
        #pragma unroll
        for (int ni = 0; ni < NI2; ni++) {
            int lcol = wn + ni * 32 + m32;
            #pragma unroll
            for (int r = 0; r < 16; r++) {
                int lrow = wm + mi * 32 + (r & 3) + 8 * (r >> 2) + 4 * hi;
                Cst[lrow * CLD + lcol] = acc[mi][ni][r];
            }
        }
    __syncthreads();
    #pragma unroll
    for (int ps = 0; ps < TM / 32; ps++) {
        int rl = ps * 32 + (tid >> 3);
        int cl = (tid & 7) * 8;
        float4 va = *(const float4*)&Cst[rl * CLD + cl];
        float4 vb = *(const float4*)&Cst[rl * CLD + cl + 4];
        float v[8] = {va.x, va.y, va.z, va.w, vb.x, vb.y, vb.z, vb.w};
        int grow = bm + rl, gcol = bn + cl;
        if (MODE == 0) {
            unsigned int xu[4] = {xpre[ps].x, xpre[ps].y, xpre[ps].z, xpre[ps].w};
            unsigned int oo[4];
            #pragma unroll
            for (int q = 0; q < 4; q++) {
                float x0 = bf2f((unsigned short)(xu[q] & 0xFFFF));
                float x1 = bf2f((unsigned short)(xu[q] >> 16));
                oo[q] = pack2(x0 * v[2 * q], x1 * v[2 * q + 1]);
            }
            uint4 ov; ov.x = oo[0]; ov.y = oo[1]; ov.z = oo[2]; ov.w = oo[3];
            size_t off = (grow < B_SZ)
                ? ((size_t)grow * COMB + gcol)
                : ((size_t)(grow - B_SZ) * COMB + FD + gcol);
            *(uint4*)&Obf[off] = ov;
        } else {
            unsigned int oo[4];
            #pragma unroll
            for (int q = 0; q < 4; q++)
                oo[q] = pack2(v[2 * q], v[2 * q + 1]);
            uint4 ov; ov.x = oo[0]; ov.y = oo[1]; ov.z = oo[2]; ov.w = oo[3];
            *(uint4*)&Obf[(size_t)grow * N + gcol] = ov;
        }
    }
}

// ---------- final: inline finalize1 + dot(w2) + sigmoid; 8 rows/block, 512 blocks ----------
__global__ __launch_bounds__(256) void final_k(const unsigned short* __restrict__ h1,
        const float* __restrict__ sum, const float* __restrict__ sumsq,
        const float* __restrict__ g, const float* __restrict__ be,
        const float* __restrict__ w2, const float* __restrict__ b2,
        const float* __restrict__ lin, const float* __restrict__ bias,
        float* __restrict__ out) {
    __shared__ float sc_s[H1], sh_s[H1], w2_s[H1];
    int t = threadIdx.x;
    int wv = t >> 6, lane = t & 63;
    int r0 = blockIdx.x * 8;
    int c0 = lane * 8;
    // front-load the h1 reads: overlap HBM latency with BN finalize + barrier
    uint4 hvv[2];
    #pragma unroll
    for (int i = 0; i < 2; i++)
        hvv[i] = *(const uint4*)&h1[(size_t)(r0 + wv * 2 + i) * H1 + c0];
    #pragma unroll
    for (int q = 0; q < 2; q++) {
        int c = q * 256 + t;
        float m = sum[c] * (1.f / B_SZ);
        float var = sumsq[c] * (1.f / B_SZ) - m * m;
        float rstd = rsqrtf(var + EPS);
        float sc = g[c] * rstd;
        sc_s[c] = sc;
        sh_s[c] = be[c] - m * sc;
        w2_s[c] = w2[c];
    }
    __syncthreads();
    #pragma unroll
    for (int i = 0; i < 2; i++) {
        int row = r0 + wv * 2 + i;
        unsigned int uu[4] = {hvv[i].x, hvv[i].y, hvv[i].z, hvv[i].w};
        float acc = 0.f;
        #pragma unroll
        for (int q = 0; q < 4; q++) {
            int c = c0 + 2 * q;
            float v0 = bf2f((unsigned short)(uu[q] & 0xFFFF)) * sc_s[c] + sh_s[c];
            float v1 = bf2f((unsigned short)(uu[q] >> 16)) * sc_s[c + 1] + sh_s[c + 1];
            acc += fmaxf(v0, 0.f) * w2_s[c] + fmaxf(v1, 0.f) * w2_s[c + 1];
        }
        #pragma unroll
        for (int off = 32; off > 0; off >>= 1) acc += __shfl_down(acc, off);
        if (lane == 0) {
            float logit = lin[row] + bias[0] + acc + b2[0];
            out[row] = 1.f / (1.f + expf(-logit));
        }
    }
}

extern "C" void kernel_launch(void* const* d_in, const int* in_sizes, int n_in,
                              void* d_out, int out_size, void* d_ws, size_t ws_size,
                              hipStream_t stream) {
    const int*   x    = (const int*)d_in[0];
    const float* emb  = (const float*)d_in[1];
    const float* lint = (const float*)d_in[2];
    const float* bias = (const float*)d_in[3];
    const float* sw1  = (const float*)d_in[4];
    const float* sw2  = (const float*)d_in[5];
    const float* bw   = (const float*)d_in[6];
    const float* w0   = (const float*)d_in[7];
    const float* b0   = (const float*)d_in[8];
    const float* g0   = (const float*)d_in[9];
    const float* be0  = (const float*)d_in[10];
    const float* w1   = (const float*)d_in[11];
    const float* b1   = (const float*)d_in[12];
    const float* g1   = (const float*)d_in[13];
    const float* be1  = (const float*)d_in[14];
    const float* w2   = (const float*)d_in[15];
    const float* b2   = (const float*)d_in[16];
    float* out = (float*)d_out;

    char* p = (char*)d_ws;
    auto alloc = [&](size_t bytes) { char* r = p; p += (bytes + 255) & ~(size_t)255; return r; };

    unsigned short* Xbf  = (unsigned short*)alloc((size_t)2 * B_SZ * FD * 2);
    unsigned short* Wt   = (unsigned short*)alloc((size_t)FD * FD * 2);
    unsigned short* w0t  = (unsigned short*)alloc((size_t)H0 * COMB * 2);
    unsigned short* w1t  = (unsigned short*)alloc((size_t)H1 * H0 * 2);
    unsigned short* Cbf  = (unsigned short*)alloc((size_t)B_SZ * COMB * 2);
    unsigned short* h0bf = (unsigned short*)alloc((size_t)B_SZ * H0 * 2);
    unsigned short* h1bf = (unsigned short*)alloc((size_t)B_SZ * H1 * 2);
    float* lin = (float*)alloc(B_SZ * 4);
    float* sums = (float*)alloc((2 * H0 + 2 * H1) * 4);
    float* sum0 = sums, *sumsq0 = sums + H0, *sum1 = sums + 2 * H0, *sumsq1 = sums + 2 * H0 + H1;

    prep_gather<<<5388, 256, 0, stream>>>(x, emb, lint, sw1, sw2, bw, w0, w1,
                                          Xbf, Wt, w0t, w1t, lin, sums);

    // S = X @ Wt^T, epilogue: Cbf = bf16(X .* S)   [768 blocks, TM=128, BK=128, 3/CU]
    mfma_gemm<0, FD, FD, 128, 64, 12, 64, 4><<<768, 256, 0, stream>>>(
        Xbf, Wt, nullptr, Xbf, Cbf, nullptr, nullptr, nullptr, nullptr, nullptr, nullptr);
    // h0 = Cbf @ w0 + b0 (+stats)   [512 blocks, TM=128, BK=128, 2/CU]
    mfma_gemm<1, COMB, H0, 128, 64, 16, 32, 4><<<512, 256, 0, stream>>>(
        Cbf, w0t, b0, nullptr, h0bf, sum0, sumsq0, nullptr, nullptr, nullptr, nullptr);
    // h1 = relu(bn(h0)) @ w1 + b1 (+stats), BN0 fused; BK=256 (4 K-iterations)
    mfma_gemm<2, H0, H1, 64, 64, 8, 64, 8><<<512, 256, 0, stream>>>(
        h0bf, w1t, b1, nullptr, h1bf, sum1, sumsq1, sum0, sumsq0, g0, be0);
    // BN1 finalize + dot + sigmoid fused
    final_k<<<B_SZ / 8, 256, 0, stream>>>(h1bf, sum1, sumsq1, g1, be1,
                                          w2, b2, lin, bias, out);
}